// Round 12
// baseline (7904.990 us; speedup 1.0000x reference)
//
#include <hip/hip_runtime.h>

// ---------- types ----------
typedef short short8 __attribute__((ext_vector_type(8)));
typedef float f32x4 __attribute__((ext_vector_type(4)));

// ---------- helpers ----------
__device__ __forceinline__ unsigned short f2bf(float x) {
  unsigned u = __builtin_bit_cast(unsigned, x);
  u += 0x7fffu + ((u >> 16) & 1u);
  return (unsigned short)(u >> 16);
}
__device__ __forceinline__ float bf2f(unsigned short v) {
  return __builtin_bit_cast(float, (unsigned)v << 16);
}
__device__ __forceinline__ float sigf(float x) { return 1.f / (1.f + __expf(-x)); }

__device__ __forceinline__ void split8(const float* __restrict__ vv, short8* h8, short8* l8) {
#pragma unroll
  for (int j = 0; j < 8; j++) {
    unsigned short hb = f2bf(vv[j]);
    unsigned short lb = f2bf(vv[j] - bf2f(hb));
    (*h8)[j] = (short)hb; (*l8)[j] = (short)lb;
  }
}
__device__ __forceinline__ void split_store8(const float* __restrict__ src,
                                             unsigned short* __restrict__ dhi,
                                             unsigned short* __restrict__ dlo) {
  float4 v0 = *(const float4*)src, v1 = *(const float4*)(src + 4);
  float vv[8] = {v0.x, v0.y, v0.z, v0.w, v1.x, v1.y, v1.z, v1.w};
  short8 h8, l8;
  split8(vv, &h8, &l8);
  *(short8*)dhi = h8; *(short8*)dlo = l8;
}

// ---------- workspace layout (~107.2 MB) ----------
static constexpr size_t OFF_GX    = 0;                                   // f32 [4096][2048] chunk
static constexpr size_t OFF_HC    = OFF_GX   + (size_t)4096*2048*4;      // f32 [4096][512] chunk
static constexpr size_t OFF_QUER  = OFF_HC   + (size_t)4096*512*4;       // f32 [32768][256]
static constexpr size_t OFF_ACTS  = OFF_QUER + (size_t)32768*256*4;      // f32 [32768][24]
static constexpr size_t OFF_R     = OFF_ACTS + (size_t)32768*24*4;       // f32 [32768][256]
static constexpr size_t OFF_HB16  = OFF_R    + (size_t)32768*256*4;      // u16 [2][2][32][512] (parity, hi/lo)
static constexpr size_t OFF_CBUF  = OFF_HB16 + (size_t)2*2*32*512*2;     // f32 [32][512]
static constexpr size_t OFF_FLAGS = OFF_CBUF + (size_t)32*512*4;         // u32 [64] (+pad)
static constexpr size_t WS_NEED   = OFF_FLAGS + 4096;
// d_out scratch: keys f32 [0:8388608), vals f32 [8388608:16777216), out_tape at 16777216

// ---------- tiny utility kernels ----------
__global__ void zero_flags_kernel(unsigned int* flags) { flags[threadIdx.x] = 0u; }
__global__ void sentinel_kernel(float* p) { p[0] = 12345.0f; }   // marks "ws too small"

// ---------- f32-accurate GEMM via bf16 hi/lo split: C[M][N] = A[M][K] @ B[N][K]^T + bias ----------
__global__ __launch_bounds__(256) void gemm_f32bt_kernel(
    const float* __restrict__ A, const float* __restrict__ Bw, float* __restrict__ C,
    const float* __restrict__ bias1, const float* __restrict__ bias2,
    int M, int N, int K) {
  const int bn = blockIdx.x, bm = blockIdx.y;
  const int tid = threadIdx.x;
  const int w = tid >> 6, l = tid & 63;
  const int wm = w >> 1, wn = w & 1;
  __shared__ __align__(16) unsigned short Ahs[128 * 40], Als[128 * 40];
  __shared__ __align__(16) unsigned short Bhs[128 * 40], Bls[128 * 40];
  f32x4 acc[4][4];
#pragma unroll
  for (int m = 0; m < 4; m++)
#pragma unroll
    for (int n = 0; n < 4; n++) acc[m][n] = (f32x4){0.f, 0.f, 0.f, 0.f};

  const int sr = tid >> 2;        // 0..63
  const int sk = (tid & 3) * 8;   // 0,8,16,24
  const size_t arow0 = (size_t)(bm * 128 + sr) * K;
  const size_t brow0 = (size_t)(bn * 128 + sr) * K;
  const int fr = l & 15, kb = (l >> 4) * 8;

  for (int kt = 0; kt < K; kt += 32) {
    __syncthreads();
    split_store8(A + arow0 + kt + sk,                  &Ahs[sr * 40 + sk],        &Als[sr * 40 + sk]);
    split_store8(A + arow0 + (size_t)64 * K + kt + sk, &Ahs[(sr + 64) * 40 + sk], &Als[(sr + 64) * 40 + sk]);
    split_store8(Bw + brow0 + kt + sk,                  &Bhs[sr * 40 + sk],        &Bls[sr * 40 + sk]);
    split_store8(Bw + brow0 + (size_t)64 * K + kt + sk, &Bhs[(sr + 64) * 40 + sk], &Bls[(sr + 64) * 40 + sk]);
    __syncthreads();
    short8 ah[4], al[4], bh[4], bl[4];
#pragma unroll
    for (int m = 0; m < 4; m++) {
      ah[m] = *(const short8*)&Ahs[(wm * 64 + m * 16 + fr) * 40 + kb];
      al[m] = *(const short8*)&Als[(wm * 64 + m * 16 + fr) * 40 + kb];
    }
#pragma unroll
    for (int n = 0; n < 4; n++) {
      bh[n] = *(const short8*)&Bhs[(wn * 64 + n * 16 + fr) * 40 + kb];
      bl[n] = *(const short8*)&Bls[(wn * 64 + n * 16 + fr) * 40 + kb];
    }
#pragma unroll
    for (int m = 0; m < 4; m++)
#pragma unroll
      for (int n = 0; n < 4; n++) {
        acc[m][n] = __builtin_amdgcn_mfma_f32_16x16x32_bf16(ah[m], bh[n], acc[m][n], 0, 0, 0);
        acc[m][n] = __builtin_amdgcn_mfma_f32_16x16x32_bf16(ah[m], bl[n], acc[m][n], 0, 0, 0);
        acc[m][n] = __builtin_amdgcn_mfma_f32_16x16x32_bf16(al[m], bh[n], acc[m][n], 0, 0, 0);
      }
  }
  const int cr = (l >> 4) * 4, cc = l & 15;
#pragma unroll
  for (int m = 0; m < 4; m++) {
#pragma unroll
    for (int n = 0; n < 4; n++) {
      int row0 = bm * 128 + wm * 64 + m * 16 + cr;
      int col = bn * 128 + wn * 64 + n * 16 + cc;
      float bv = bias1 ? bias1[col] : 0.f;
      if (bias2) bv += bias2[col];
#pragma unroll
      for (int r = 0; r < 4; r++) C[(size_t)(row0 + r) * N + col] = acc[m][n][r] + bv;
    }
  }
}

// ---------- unit-norm over contiguous 64-element groups ----------
__global__ __launch_bounds__(256) void norm64_kernel(float* __restrict__ buf) {
  int g = blockIdx.x * 4 + (threadIdx.x >> 6);
  int lane = threadIdx.x & 63;
  float x = buf[(size_t)g * 64 + lane];
  float s = x * x;
#pragma unroll
  for (int m = 1; m < 64; m <<= 1) s += __shfl_xor(s, m, 64);
  buf[(size_t)g * 64 + lane] = x / fmaxf(sqrtf(s), 1e-12f);
}

// ---------- weight-stationary LSTM chunk (r4-verified protocol; 3-chain MFMA) ----------
// block g owns hidden units [g*8, g*8+8); local gate rows: 0-7=i, 8-15=f, 16-23=g, 24-31=o
__global__ __launch_bounds__(256) void lstm_kernel(const float* __restrict__ gxc,   // [4096][2048] chunk
                                                   const float* __restrict__ Whh,
                                                   unsigned short* __restrict__ hb16, // [2][2][32][512]
                                                   float* __restrict__ cbuf,
                                                   unsigned int* __restrict__ flags,
                                                   float* __restrict__ Hc,          // [4096][512] chunk
                                                   int t0) {
  const int g = blockIdx.x;
  const int u0 = g * 8;
  const int tid = threadIdx.x;
  const int l = tid & 63, w = tid >> 6;
  __shared__ __align__(16) unsigned short Whi[32 * 512], Wlo[32 * 512];
  __shared__ __align__(16) unsigned short hhi[32 * 512], hlo[32 * 512];
  __shared__ float gates[32][33];

  // ---- load + split weights (swizzled: k-group kg stored at kg^(row&7)) ----
  {
    int r = tid >> 3, seg = tid & 7;
    int grow = (r >> 3) * 512 + u0 + (r & 7);
    const float* src = Whh + (size_t)grow * 512 + seg * 64;
#pragma unroll
    for (int i0 = 0; i0 < 64; i0 += 8) {
      int kg = seg * 8 + (i0 >> 3);
      int phys = r * 512 + ((kg ^ (r & 7)) << 3);
      split_store8(src + i0, &Whi[phys], &Wlo[phys]);
    }
  }
  if (t0 == 0) {
    for (int i = tid * 8; i < 32 * 512; i += 256 * 8) {
      short8 z = {0, 0, 0, 0, 0, 0, 0, 0};
      *(short8*)&hhi[i] = z; *(short8*)&hlo[i] = z;
    }
  }
  const int bb = tid >> 3, jj = tid & 7;   // (batch, unit) ownership for nonlinearity
  float c = (t0 == 0) ? 0.f : cbuf[bb * 512 + u0 + jj];
  const int m = w >> 1, n = w & 1;
  const int arow = m * 16 + (l & 15), brow = n * 16 + (l & 15);
  const int asw = arow & 7, bsw = brow & 7;
  const int kq = l >> 4;
  __syncthreads();

  for (int t = t0; t < t0 + 128; ++t) {
    // prefetch gx for this step (independent of h -> completes during flag spin)
    const float* gxr = gxc + ((size_t)(t - t0) * 32 + bb) * 2048;
    float xgi = gxr[u0 + jj];
    float xgf = gxr[512 + u0 + jj];
    float xgg = gxr[1024 + u0 + jj];
    float xgo = gxr[1536 + u0 + jj];
    if (t > 0) {
      if (tid < 64) {
        while (__hip_atomic_load(&flags[tid], __ATOMIC_RELAXED, __HIP_MEMORY_SCOPE_AGENT) < (unsigned)t)
          __builtin_amdgcn_s_sleep(1);
      }
      __syncthreads();
      // reload h(t-1): pre-split planes, straight copy into swizzled LDS
      const size_t pbase = (size_t)(t & 1) * 2 * 16384;
      const unsigned long long* hbh = (const unsigned long long*)(hb16 + pbase);
      const unsigned long long* hbl = (const unsigned long long*)(hb16 + pbase + 16384);
#pragma unroll
      for (int g8 = 0; g8 < 8; g8++) {
        int idx = g8 * 2048 + tid * 8;          // u16 index within plane
        unsigned long long h0 = __hip_atomic_load(hbh + (idx >> 2),     __ATOMIC_RELAXED, __HIP_MEMORY_SCOPE_AGENT);
        unsigned long long h1 = __hip_atomic_load(hbh + (idx >> 2) + 1, __ATOMIC_RELAXED, __HIP_MEMORY_SCOPE_AGENT);
        unsigned long long l0 = __hip_atomic_load(hbl + (idx >> 2),     __ATOMIC_RELAXED, __HIP_MEMORY_SCOPE_AGENT);
        unsigned long long l1 = __hip_atomic_load(hbl + (idx >> 2) + 1, __ATOMIC_RELAXED, __HIP_MEMORY_SCOPE_AGENT);
        int b = idx >> 9, kg = (idx >> 3) & 63;
        int phys = b * 512 + ((kg ^ (b & 7)) << 3);
        *(unsigned long long*)&hhi[phys] = h0; *(unsigned long long*)&hhi[phys + 4] = h1;
        *(unsigned long long*)&hlo[phys] = l0; *(unsigned long long*)&hlo[phys + 4] = l1;
      }
      __syncthreads();
    }
    // ---- gates = h @ Wrows^T, split MFMA: 3 INDEPENDENT accumulator chains ----
    f32x4 acc0 = (f32x4){0.f, 0.f, 0.f, 0.f};
    f32x4 acc1 = (f32x4){0.f, 0.f, 0.f, 0.f};
    f32x4 acc2 = (f32x4){0.f, 0.f, 0.f, 0.f};
#pragma unroll
    for (int kt = 0; kt < 16; kt++) {
      int kg = kt * 4 + kq;
      short8 ah = *(const short8*)&hhi[arow * 512 + ((kg ^ asw) << 3)];
      short8 al = *(const short8*)&hlo[arow * 512 + ((kg ^ asw) << 3)];
      short8 bh = *(const short8*)&Whi[brow * 512 + ((kg ^ bsw) << 3)];
      short8 bl = *(const short8*)&Wlo[brow * 512 + ((kg ^ bsw) << 3)];
      acc0 = __builtin_amdgcn_mfma_f32_16x16x32_bf16(ah, bh, acc0, 0, 0, 0);
      acc1 = __builtin_amdgcn_mfma_f32_16x16x32_bf16(ah, bl, acc1, 0, 0, 0);
      acc2 = __builtin_amdgcn_mfma_f32_16x16x32_bf16(al, bh, acc2, 0, 0, 0);
    }
    {
      f32x4 accs = acc0 + acc1 + acc2;
      int jcol = n * 16 + (l & 15), i0r = m * 16 + (l >> 4) * 4;
#pragma unroll
      for (int r = 0; r < 4; r++) gates[jcol][i0r + r] = accs[r];
    }
    __syncthreads();
    // ---- nonlinearity for (batch bb, unit u0+jj) ----
    {
      float gi = gates[jj][bb]      + xgi;
      float gf = gates[8 + jj][bb]  + xgf;
      float gg = gates[16 + jj][bb] + xgg;
      float go = gates[24 + jj][bb] + xgo;
      c = sigf(gf) * c + sigf(gi) * tanhf(gg);
      float h = sigf(go) * tanhf(c);
      Hc[((size_t)(t - t0) * 32 + bb) * 512 + u0 + jj] = h;
      unsigned short hi16 = f2bf(h);
      unsigned short lo16 = f2bf(h - bf2f(hi16));
      const size_t pb2 = (size_t)((t + 1) & 1) * 2 * 16384;
      __hip_atomic_store(hb16 + pb2 + bb * 512 + u0 + jj, hi16,
                         __ATOMIC_RELAXED, __HIP_MEMORY_SCOPE_AGENT);
      __hip_atomic_store(hb16 + pb2 + 16384 + bb * 512 + u0 + jj, lo16,
                         __ATOMIC_RELAXED, __HIP_MEMORY_SCOPE_AGENT);
    }
    __syncthreads();   // drains vmcnt(0): h stores globally visible (sc1 -> L3) before flag
    if (tid == 0)
      __hip_atomic_store(&flags[g], (unsigned)(t + 1), __ATOMIC_RELAXED, __HIP_MEMORY_SCOPE_AGENT);
  }
  cbuf[bb * 512 + u0 + jj] = c;
}

// ---------- actions head: wave per row (chunk-local) ----------
__global__ __launch_bounds__(256) void actions_kernel(const float* __restrict__ H,
                                                      const float* __restrict__ Wact,
                                                      const float* __restrict__ bact,
                                                      float* __restrict__ acts) {
  const int wrow = threadIdx.x >> 6;
  const int row = blockIdx.x * 4 + wrow;
  const int lane = threadIdx.x & 63;
  __shared__ float a_s[4][24];
  const float* hp = H + (size_t)row * 512 + lane * 8;
  float4 h0 = *(const float4*)hp, h1 = *(const float4*)(hp + 4);
  float hf[8] = {h0.x, h0.y, h0.z, h0.w, h1.x, h1.y, h1.z, h1.w};
#pragma unroll
  for (int j = 0; j < 24; j++) {
    const float4* wr = (const float4*)(Wact + (size_t)j * 512 + lane * 8);
    float4 w0 = wr[0], w1 = wr[1];
    float p = hf[0] * w0.x + hf[1] * w0.y + hf[2] * w0.z + hf[3] * w0.w +
              hf[4] * w1.x + hf[5] * w1.y + hf[6] * w1.z + hf[7] * w1.w;
#pragma unroll
    for (int mm = 1; mm < 64; mm <<= 1) p += __shfl_xor(p, mm, 64);
    if (lane == j) a_s[wrow][j] = p + bact[j];
  }
  __syncthreads();
  if (lane < 4) {
    float av[6];
#pragma unroll
    for (int i = 0; i < 6; i++) av[i] = a_s[wrow][lane * 6 + i];
    float* o = acts + (size_t)row * 24 + lane * 6;
    o[0] = sigf(av[0] - av[1]); o[1] = sigf(av[1] - av[0]);
    o[2] = sigf(av[2] - av[3]); o[3] = sigf(av[3] - av[2]);
    o[4] = sigf(av[4]); o[5] = sigf(av[5]);
  }
}

// ---------- sequential tape scan: 1024 threads, wave-specialized, 2 barriers/step ----------
// Exact identities:  read_out[c] = prC[c] + (wpos.rpos)*dv[c]
//                    jpos[l] = jq[l] + wpos[l]*(dk.q)
// Norm computed DIRECTLY as s = sum jp^2 (shuffle) - structurally non-negative.
// (Round-11's flattened quadratic a+2dq*b+dq^2*c cancels catastrophically -> NaN. Reverted.)
// Phase1 (single-stage): w0: ov->dv | w3: ok->dk | w1: prC | w2: jq.
// Phase2: all waves update 4 rows; w1: Rout; w2: dq shuffle -> jp -> s shuffle -> pos advance; w0: publish q.
__global__ __launch_bounds__(1024) void tape_kernel(const float* __restrict__ vals,
                                                    const float* __restrict__ keys,
                                                    const float* __restrict__ quer,
                                                    const float* __restrict__ acts,
                                                    float* __restrict__ Rout,
                                                    float* __restrict__ out_tape) {
  const int bid = blockIdx.x;          // 0..127
  const int b = bid >> 2, nt = bid & 3;
  const int tid = threadIdx.x;
  const int cid = tid & 63, lg = tid >> 6;   // lg 0..15
  __shared__ float tape[64][65], tkey[64][65];
  __shared__ float dv_s[64], dk_s[64];
  __shared__ float wpos_s[2][64], rpos_s[2][64], q_s[2][64];
  for (int i = tid; i < 64 * 65; i += 1024) { ((float*)tape)[i] = 0.f; ((float*)tkey)[i] = 0.f; }
  if (tid < 64) {
    wpos_s[0][tid] = (tid == 0) ? 1.f : 0.f;
    rpos_s[0][tid] = (tid == 0) ? 1.f : 0.f;
  }

  // prefetch t=0 inputs (wave0: v,q ; wave3: k ; waves 0-3: acts)
  float pv = 0.f, pk = 0.f, pq = 0.f;
  float2 pa0 = make_float2(0.f, 0.f), pa1 = pa0, pa2 = pa0;
  {
    const size_t rc0 = ((size_t)b * 4 + nt) * 64;
    const float* a60 = acts + (size_t)b * 24 + nt * 6;
    if (lg == 0) { pv = vals[rc0 + cid]; pq = quer[rc0 + cid]; }
    if (lg == 3) { pk = keys[rc0 + cid]; }
    if (lg < 4) {
      pa0 = *(const float2*)(a60); pa1 = *(const float2*)(a60 + 2); pa2 = *(const float2*)(a60 + 4);
    }
  }
  if (lg == 0) q_s[0][cid] = pq;
  __syncthreads();

  float prC = 0.f;
  for (int t = 0; t < 1024; ++t) {
    const int p = t & 1;
    const float v = pv, k = pk;
    const float rd0 = pa0.x, rd1 = pa0.y, wd0 = pa1.x, wd1 = pa1.y, rw0 = pa2.x, rw1 = pa2.y;
    const size_t rc = (((size_t)t * 32 + b) * 4 + nt) * 64;
    // issue prefetch t+1 (hidden under both phases)
    {
      int tn = (t + 1 < 1024) ? t + 1 : 1023;
      const size_t rbn = (size_t)tn * 32 + b;
      const size_t rcn = (rbn * 4 + nt) * 64;
      const float* a6n = acts + rbn * 24 + nt * 6;
      if (lg == 0) { pv = vals[rcn + cid]; pq = quer[rcn + cid]; }
      if (lg == 3) { pk = keys[rcn + cid]; }
      if (lg < 4) {
        pa0 = *(const float2*)(a6n); pa1 = *(const float2*)(a6n + 2); pa2 = *(const float2*)(a6n + 4);
      }
    }
    // ---- phase 1: wave-specialized single-stage reductions ----
    float jq = 0.f;
    if (lg == 0) {
      float ov = 0.f;
#pragma unroll
      for (int l2 = 0; l2 < 64; l2++) ov = fmaf(tape[l2][cid], wpos_s[p][l2], ov);
      dv_s[cid] = (v - ov) * rw1;
    } else if (lg == 3) {
      float ok = 0.f;
#pragma unroll
      for (int l2 = 0; l2 < 64; l2++) ok = fmaf(tkey[l2][cid], wpos_s[p][l2], ok);
      dk_s[cid] = (k - ok) * rw1;
    } else if (lg == 1) {
      prC = 0.f;
#pragma unroll
      for (int l2 = 0; l2 < 64; l2++) prC = fmaf(tape[l2][cid], rpos_s[p][l2], prC);
    } else if (lg == 2) {
#pragma unroll
      for (int c2 = 0; c2 < 64; c2++) jq = fmaf(tkey[cid][c2], q_s[p][c2], jq);
    }
    __syncthreads();  // S1: dv_s/dk_s visible; all phase-1 reads of tape/tkey done
    // ---- phase 2: updates (all 16 waves) + epilogues ----
    const float dvc = dv_s[cid], dkc = dk_s[cid];
#pragma unroll
    for (int i = 0; i < 4; i++) {
      int l2 = lg * 4 + i;
      float wp = wpos_s[p][l2];
      tape[l2][cid] = fmaf(wp, dvc, tape[l2][cid]);
      tkey[l2][cid] = fmaf(wp, dkc, tkey[l2][cid]);
    }
    if (lg == 0) {
      q_s[p ^ 1][cid] = pq;                       // publish q(t+1)
    } else if (lg == 1) {
      float sw = wpos_s[p][cid] * rpos_s[p][cid];
#pragma unroll
      for (int mm = 1; mm < 64; mm <<= 1) sw += __shfl_xor(sw, mm, 64);
      Rout[rc + cid] = fmaf(sw, dvc, prC) * rw0;
    } else if (lg == 2) {
      float dq = dkc * q_s[p][cid];
#pragma unroll
      for (int mm = 1; mm < 64; mm <<= 1) dq += __shfl_xor(dq, mm, 64);
      float jp = fmaf(wpos_s[p][cid], dq, jq);
      float s = jp * jp;
#pragma unroll
      for (int mm = 1; mm < 64; mm <<= 1) s += __shfl_xor(s, mm, 64);
      jp /= fmaxf(sqrtf(s), 1e-12f);
      rpos_s[p ^ 1][cid] = rpos_s[p][cid] * rd0 + jp * rd1;
      wpos_s[p ^ 1][cid] = wpos_s[p][cid] * wd0 + jp * wd1;
    }
    __syncthreads();  // S2: tape/tkey updates + new pos/q visible for next phase 1
  }
  // final tape -> out_tape[(l*32+b)*256 + nt*64 + c]
  for (int i = tid; i < 4096; i += 1024) {
    int l2 = i >> 6, c2 = i & 63;
    out_tape[((size_t)l2 * 32 + b) * 256 + nt * 64 + c2] = tape[l2][c2];
  }
}

// ---------- launcher ----------
extern "C" void kernel_launch(void* const* d_in, const int* in_sizes, int n_in,
                              void* d_out, int out_size, void* d_ws, size_t ws_size,
                              hipStream_t stream) {
  const float* inputs = (const float*)d_in[0];
  const float* W_ih = (const float*)d_in[1];
  const float* W_hh = (const float*)d_in[2];
  const float* b_ih = (const float*)d_in[3];
  const float* b_hh = (const float*)d_in[4];
  const float* W_act = (const float*)d_in[5];
  const float* b_act = (const float*)d_in[6];
  const float* W_val = (const float*)d_in[7];
  const float* b_val = (const float*)d_in[8];
  const float* W_key = (const float*)d_in[9];
  const float* b_key = (const float*)d_in[10];
  const float* W_q = (const float*)d_in[11];
  const float* b_q = (const float*)d_in[12];
  const float* W_out = (const float*)d_in[13];
  const float* b_out = (const float*)d_in[14];

  if (ws_size < WS_NEED) {           // sentinel: absmax ~= 12345 tells us ws is too small
    sentinel_kernel<<<1, 1, 0, stream>>>((float*)d_out);
    return;
  }

  char* ws = (char*)d_ws;
  float* gxbuf = (float*)(ws + OFF_GX);
  float* Hc = (float*)(ws + OFF_HC);
  float* quer = (float*)(ws + OFF_QUER);
  float* acts = (float*)(ws + OFF_ACTS);
  float* R = (float*)(ws + OFF_R);
  unsigned short* hb16 = (unsigned short*)(ws + OFF_HB16);
  float* cbuf = (float*)(ws + OFF_CBUF);
  unsigned int* flags = (unsigned int*)(ws + OFF_FLAGS);

  float* keys = (float*)d_out;               // scratch in d_out (consumed by tape, then overwritten)
  float* vals = (float*)d_out + 8388608;
  float* out_tape = (float*)d_out + 16777216;

  dim3 blk(256);
  zero_flags_kernel<<<1, 64, 0, stream>>>(flags);

  gemm_f32bt_kernel<<<dim3(2, 256), blk, 0, stream>>>(inputs, W_val, vals, b_val, nullptr, 32768, 256, 512);
  gemm_f32bt_kernel<<<dim3(2, 256), blk, 0, stream>>>(inputs, W_key, keys, b_key, nullptr, 32768, 256, 512);
  norm64_kernel<<<32768, blk, 0, stream>>>(keys);

  for (int q = 0; q < 8; q++) {
    const float* Achunk = inputs + (size_t)q * 4096 * 512;
    gemm_f32bt_kernel<<<dim3(16, 32), blk, 0, stream>>>(Achunk, W_ih, gxbuf, b_ih, b_hh, 4096, 2048, 512);
    lstm_kernel<<<64, blk, 0, stream>>>(gxbuf, W_hh, hb16, cbuf, flags, Hc, q * 128);
    gemm_f32bt_kernel<<<dim3(2, 32), blk, 0, stream>>>(Hc, W_q, quer + (size_t)q * 4096 * 256, b_q, nullptr, 4096, 256, 512);
    actions_kernel<<<1024, blk, 0, stream>>>(Hc, W_act, b_act, acts + (size_t)q * 4096 * 24);
  }
  norm64_kernel<<<32768, blk, 0, stream>>>(quer);

  tape_kernel<<<128, 1024, 0, stream>>>(vals, keys, quer, acts, R, out_tape);

  gemm_f32bt_kernel<<<dim3(4, 256), blk, 0, stream>>>(R, W_out, (float*)d_out, b_out, nullptr, 32768, 512, 256);
}

// Round 13
// 6436.445 us; speedup vs baseline: 1.2282x; 1.2282x over previous
//
#include <hip/hip_runtime.h>

// ---------- types ----------
typedef short short8 __attribute__((ext_vector_type(8)));
typedef float f32x4 __attribute__((ext_vector_type(4)));

// addrspace cast helpers for global_load_lds
#define GP(p) ((const __attribute__((address_space(1))) void*)(p))
#define SP(p) ((__attribute__((address_space(3))) void*)(p))

// ---------- helpers ----------
__device__ __forceinline__ unsigned short f2bf(float x) {
  unsigned u = __builtin_bit_cast(unsigned, x);
  u += 0x7fffu + ((u >> 16) & 1u);
  return (unsigned short)(u >> 16);
}
__device__ __forceinline__ float bf2f(unsigned short v) {
  return __builtin_bit_cast(float, (unsigned)v << 16);
}
__device__ __forceinline__ float sigf(float x) { return 1.f / (1.f + __expf(-x)); }

__device__ __forceinline__ void split8(const float* __restrict__ vv, short8* h8, short8* l8) {
#pragma unroll
  for (int j = 0; j < 8; j++) {
    unsigned short hb = f2bf(vv[j]);
    unsigned short lb = f2bf(vv[j] - bf2f(hb));
    (*h8)[j] = (short)hb; (*l8)[j] = (short)lb;
  }
}
__device__ __forceinline__ void split_store8(const float* __restrict__ src,
                                             unsigned short* __restrict__ dhi,
                                             unsigned short* __restrict__ dlo) {
  float4 v0 = *(const float4*)src, v1 = *(const float4*)(src + 4);
  float vv[8] = {v0.x, v0.y, v0.z, v0.w, v1.x, v1.y, v1.z, v1.w};
  short8 h8, l8;
  split8(vv, &h8, &l8);
  *(short8*)dhi = h8; *(short8*)dlo = l8;
}

// ---------- workspace layout (~107.2 MB) ----------
static constexpr size_t OFF_GX    = 0;                                   // f32 [4096][2048] chunk
static constexpr size_t OFF_HC    = OFF_GX   + (size_t)4096*2048*4;      // f32 [4096][512] chunk
static constexpr size_t OFF_QUER  = OFF_HC   + (size_t)4096*512*4;       // f32 [32768][256]
static constexpr size_t OFF_ACTS  = OFF_QUER + (size_t)32768*256*4;      // f32 [32768][24]
static constexpr size_t OFF_R     = OFF_ACTS + (size_t)32768*24*4;       // f32 [32768][256]
static constexpr size_t OFF_HB16  = OFF_R    + (size_t)32768*256*4;      // u16 [2][2][32][512] (parity, hi/lo)
static constexpr size_t OFF_CBUF  = OFF_HB16 + (size_t)2*2*32*512*2;     // f32 [32][512]
static constexpr size_t OFF_FLAGS = OFF_CBUF + (size_t)32*512*4;         // u32 [64] (+pad)
static constexpr size_t WS_NEED   = OFF_FLAGS + 4096;
// d_out scratch: keys f32 [0:8388608), vals f32 [8388608:16777216), out_tape at 16777216

// ---------- tiny utility kernels ----------
__global__ void zero_flags_kernel(unsigned int* flags) { flags[threadIdx.x] = 0u; }
__global__ void sentinel_kernel(float* p) { p[0] = 12345.0f; }   // marks "ws too small"

// ---------- f32-accurate GEMM via bf16 hi/lo split: C[M][N] = A[M][K] @ B[N][K]^T + bias ----------
__global__ __launch_bounds__(256) void gemm_f32bt_kernel(
    const float* __restrict__ A, const float* __restrict__ Bw, float* __restrict__ C,
    const float* __restrict__ bias1, const float* __restrict__ bias2,
    int M, int N, int K) {
  const int bn = blockIdx.x, bm = blockIdx.y;
  const int tid = threadIdx.x;
  const int w = tid >> 6, l = tid & 63;
  const int wm = w >> 1, wn = w & 1;
  __shared__ __align__(16) unsigned short Ahs[128 * 40], Als[128 * 40];
  __shared__ __align__(16) unsigned short Bhs[128 * 40], Bls[128 * 40];
  f32x4 acc[4][4];
#pragma unroll
  for (int m = 0; m < 4; m++)
#pragma unroll
    for (int n = 0; n < 4; n++) acc[m][n] = (f32x4){0.f, 0.f, 0.f, 0.f};

  const int sr = tid >> 2;        // 0..63
  const int sk = (tid & 3) * 8;   // 0,8,16,24
  const size_t arow0 = (size_t)(bm * 128 + sr) * K;
  const size_t brow0 = (size_t)(bn * 128 + sr) * K;
  const int fr = l & 15, kb = (l >> 4) * 8;

  for (int kt = 0; kt < K; kt += 32) {
    __syncthreads();
    split_store8(A + arow0 + kt + sk,                  &Ahs[sr * 40 + sk],        &Als[sr * 40 + sk]);
    split_store8(A + arow0 + (size_t)64 * K + kt + sk, &Ahs[(sr + 64) * 40 + sk], &Als[(sr + 64) * 40 + sk]);
    split_store8(Bw + brow0 + kt + sk,                  &Bhs[sr * 40 + sk],        &Bls[sr * 40 + sk]);
    split_store8(Bw + brow0 + (size_t)64 * K + kt + sk, &Bhs[(sr + 64) * 40 + sk], &Bls[(sr + 64) * 40 + sk]);
    __syncthreads();
    short8 ah[4], al[4], bh[4], bl[4];
#pragma unroll
    for (int m = 0; m < 4; m++) {
      ah[m] = *(const short8*)&Ahs[(wm * 64 + m * 16 + fr) * 40 + kb];
      al[m] = *(const short8*)&Als[(wm * 64 + m * 16 + fr) * 40 + kb];
    }
#pragma unroll
    for (int n = 0; n < 4; n++) {
      bh[n] = *(const short8*)&Bhs[(wn * 64 + n * 16 + fr) * 40 + kb];
      bl[n] = *(const short8*)&Bls[(wn * 64 + n * 16 + fr) * 40 + kb];
    }
#pragma unroll
    for (int m = 0; m < 4; m++)
#pragma unroll
      for (int n = 0; n < 4; n++) {
        acc[m][n] = __builtin_amdgcn_mfma_f32_16x16x32_bf16(ah[m], bh[n], acc[m][n], 0, 0, 0);
        acc[m][n] = __builtin_amdgcn_mfma_f32_16x16x32_bf16(ah[m], bl[n], acc[m][n], 0, 0, 0);
        acc[m][n] = __builtin_amdgcn_mfma_f32_16x16x32_bf16(al[m], bh[n], acc[m][n], 0, 0, 0);
      }
  }
  const int cr = (l >> 4) * 4, cc = l & 15;
#pragma unroll
  for (int m = 0; m < 4; m++) {
#pragma unroll
    for (int n = 0; n < 4; n++) {
      int row0 = bm * 128 + wm * 64 + m * 16 + cr;
      int col = bn * 128 + wn * 64 + n * 16 + cc;
      float bv = bias1 ? bias1[col] : 0.f;
      if (bias2) bv += bias2[col];
#pragma unroll
      for (int r = 0; r < 4; r++) C[(size_t)(row0 + r) * N + col] = acc[m][n][r] + bv;
    }
  }
}

// ---------- unit-norm over contiguous 64-element groups ----------
__global__ __launch_bounds__(256) void norm64_kernel(float* __restrict__ buf) {
  int g = blockIdx.x * 4 + (threadIdx.x >> 6);
  int lane = threadIdx.x & 63;
  float x = buf[(size_t)g * 64 + lane];
  float s = x * x;
#pragma unroll
  for (int m = 1; m < 64; m <<= 1) s += __shfl_xor(s, m, 64);
  buf[(size_t)g * 64 + lane] = x / fmaxf(sqrtf(s), 1e-12f);
}

// ---------- weight-stationary LSTM chunk: r4 protocol + global_load_lds reload ----------
// block g owns hidden units [g*8, g*8+8); local gate rows: 0-7=i, 8-15=f, 16-23=g, 24-31=o
// h exchange: pre-split bf16 hi/lo planes in L3 (producer: agent-relaxed stores, sc1).
// Reload: 16 global_load_lds per wave (aux=16 -> SC1, bypass non-coherent L2), linear LDS dest,
// pre-swizzled global source (XOR applied on source address; coalesced within 128B windows).
__global__ __launch_bounds__(256) void lstm_kernel(const float* __restrict__ gxc,   // [4096][2048] chunk
                                                   const float* __restrict__ Whh,
                                                   unsigned short* __restrict__ hb16, // [2][2][32][512]
                                                   float* __restrict__ cbuf,
                                                   unsigned int* __restrict__ flags,
                                                   float* __restrict__ Hc,          // [4096][512] chunk
                                                   int t0) {
  const int g = blockIdx.x;
  const int u0 = g * 8;
  const int tid = threadIdx.x;
  const int l = tid & 63, w = tid >> 6;
  __shared__ __align__(16) unsigned short Whi[32 * 512], Wlo[32 * 512];
  __shared__ __align__(16) unsigned short hhi[32 * 512], hlo[32 * 512];
  __shared__ float gates[32][33];

  // ---- load + split weights (swizzled: k-group kg stored at kg^(row&7)) ----
  {
    int r = tid >> 3, seg = tid & 7;
    int grow = (r >> 3) * 512 + u0 + (r & 7);
    const float* src = Whh + (size_t)grow * 512 + seg * 64;
#pragma unroll
    for (int i0 = 0; i0 < 64; i0 += 8) {
      int kg = seg * 8 + (i0 >> 3);
      int phys = r * 512 + ((kg ^ (r & 7)) << 3);
      split_store8(src + i0, &Whi[phys], &Wlo[phys]);
    }
  }
  if (t0 == 0) {
    for (int i = tid * 8; i < 32 * 512; i += 256 * 8) {
      short8 z = {0, 0, 0, 0, 0, 0, 0, 0};
      *(short8*)&hhi[i] = z; *(short8*)&hlo[i] = z;
    }
  }
  const int bb = tid >> 3, jj = tid & 7;   // (batch, unit) ownership for nonlinearity
  float c = (t0 == 0) ? 0.f : cbuf[bb * 512 + u0 + jj];
  const int m = w >> 1, n = w & 1;
  const int arow = m * 16 + (l & 15), brow2 = n * 16 + (l & 15);
  const int asw = arow & 7, bsw = brow2 & 7;
  const int kq = l >> 4;
  __syncthreads();

  for (int t = t0; t < t0 + 128; ++t) {
    // prefetch gx for this step (independent of h -> completes during flag spin)
    const float* gxr = gxc + ((size_t)(t - t0) * 32 + bb) * 2048;
    float xgi = gxr[u0 + jj];
    float xgf = gxr[512 + u0 + jj];
    float xgg = gxr[1024 + u0 + jj];
    float xgo = gxr[1536 + u0 + jj];
    if (t > 0) {
      if (tid < 64) {
        while (__hip_atomic_load(&flags[tid], __ATOMIC_RELAXED, __HIP_MEMORY_SCOPE_AGENT) < (unsigned)t)
          __builtin_amdgcn_s_sleep(1);
      }
      __syncthreads();
      // reload h(t-1): direct L3 -> LDS. Instruction (j, wave w) covers batch row brow = j*4+w:
      // LDS byte brow*1024 + lane*16  <-  global byte brow*1024 + ((lane^(brow&7))<<4).
      {
        const unsigned char* hbase = (const unsigned char*)hb16 + (size_t)(t & 1) * 65536;
        char* hhi_b = (char*)hhi;
        char* hlo_b = (char*)hlo;
#pragma unroll
        for (int j = 0; j < 8; j++) {
          int br = j * 4 + w;
          int soff = br * 1024 + ((l ^ (br & 7)) << 4);
          __builtin_amdgcn_global_load_lds(GP(hbase + soff),         SP(hhi_b + br * 1024), 16, 0, 16);
          __builtin_amdgcn_global_load_lds(GP(hbase + 32768 + soff), SP(hlo_b + br * 1024), 16, 0, 16);
        }
      }
      __syncthreads();   // drains vmcnt(0): all gload_lds data landed in LDS
    }
    // ---- gates = h @ Wrows^T, split MFMA: 3 INDEPENDENT accumulator chains ----
    f32x4 acc0 = (f32x4){0.f, 0.f, 0.f, 0.f};
    f32x4 acc1 = (f32x4){0.f, 0.f, 0.f, 0.f};
    f32x4 acc2 = (f32x4){0.f, 0.f, 0.f, 0.f};
#pragma unroll
    for (int kt = 0; kt < 16; kt++) {
      int kg = kt * 4 + kq;
      short8 ah = *(const short8*)&hhi[arow * 512 + ((kg ^ asw) << 3)];
      short8 al = *(const short8*)&hlo[arow * 512 + ((kg ^ asw) << 3)];
      short8 bh = *(const short8*)&Whi[brow2 * 512 + ((kg ^ bsw) << 3)];
      short8 bl = *(const short8*)&Wlo[brow2 * 512 + ((kg ^ bsw) << 3)];
      acc0 = __builtin_amdgcn_mfma_f32_16x16x32_bf16(ah, bh, acc0, 0, 0, 0);
      acc1 = __builtin_amdgcn_mfma_f32_16x16x32_bf16(ah, bl, acc1, 0, 0, 0);
      acc2 = __builtin_amdgcn_mfma_f32_16x16x32_bf16(al, bh, acc2, 0, 0, 0);
    }
    {
      f32x4 accs = acc0 + acc1 + acc2;
      int jcol = n * 16 + (l & 15), i0r = m * 16 + (l >> 4) * 4;
#pragma unroll
      for (int r = 0; r < 4; r++) gates[jcol][i0r + r] = accs[r];
    }
    __syncthreads();
    // ---- nonlinearity for (batch bb, unit u0+jj) ----
    {
      float gi = gates[jj][bb]      + xgi;
      float gf = gates[8 + jj][bb]  + xgf;
      float gg = gates[16 + jj][bb] + xgg;
      float go = gates[24 + jj][bb] + xgo;
      c = sigf(gf) * c + sigf(gi) * tanhf(gg);
      float h = sigf(go) * tanhf(c);
      Hc[((size_t)(t - t0) * 32 + bb) * 512 + u0 + jj] = h;
      unsigned short hi16 = f2bf(h);
      unsigned short lo16 = f2bf(h - bf2f(hi16));
      const size_t pb2 = (size_t)((t + 1) & 1) * 2 * 16384;
      __hip_atomic_store(hb16 + pb2 + bb * 512 + u0 + jj, hi16,
                         __ATOMIC_RELAXED, __HIP_MEMORY_SCOPE_AGENT);
      __hip_atomic_store(hb16 + pb2 + 16384 + bb * 512 + u0 + jj, lo16,
                         __ATOMIC_RELAXED, __HIP_MEMORY_SCOPE_AGENT);
    }
    __syncthreads();   // drains vmcnt(0): h stores globally visible (sc1 -> L3) before flag
    if (tid == 0)
      __hip_atomic_store(&flags[g], (unsigned)(t + 1), __ATOMIC_RELAXED, __HIP_MEMORY_SCOPE_AGENT);
  }
  cbuf[bb * 512 + u0 + jj] = c;
}

// ---------- actions head: wave per row (chunk-local) ----------
__global__ __launch_bounds__(256) void actions_kernel(const float* __restrict__ H,
                                                      const float* __restrict__ Wact,
                                                      const float* __restrict__ bact,
                                                      float* __restrict__ acts) {
  const int wrow = threadIdx.x >> 6;
  const int row = blockIdx.x * 4 + wrow;
  const int lane = threadIdx.x & 63;
  __shared__ float a_s[4][24];
  const float* hp = H + (size_t)row * 512 + lane * 8;
  float4 h0 = *(const float4*)hp, h1 = *(const float4*)(hp + 4);
  float hf[8] = {h0.x, h0.y, h0.z, h0.w, h1.x, h1.y, h1.z, h1.w};
#pragma unroll
  for (int j = 0; j < 24; j++) {
    const float4* wr = (const float4*)(Wact + (size_t)j * 512 + lane * 8);
    float4 w0 = wr[0], w1 = wr[1];
    float p = hf[0] * w0.x + hf[1] * w0.y + hf[2] * w0.z + hf[3] * w0.w +
              hf[4] * w1.x + hf[5] * w1.y + hf[6] * w1.z + hf[7] * w1.w;
#pragma unroll
    for (int mm = 1; mm < 64; mm <<= 1) p += __shfl_xor(p, mm, 64);
    if (lane == j) a_s[wrow][j] = p + bact[j];
  }
  __syncthreads();
  if (lane < 4) {
    float av[6];
#pragma unroll
    for (int i = 0; i < 6; i++) av[i] = a_s[wrow][lane * 6 + i];
    float* o = acts + (size_t)row * 24 + lane * 6;
    o[0] = sigf(av[0] - av[1]); o[1] = sigf(av[1] - av[0]);
    o[2] = sigf(av[2] - av[3]); o[3] = sigf(av[3] - av[2]);
    o[4] = sigf(av[4]); o[5] = sigf(av[5]);
  }
}

// ---------- sequential tape scan (r10-verified best): 1024 threads, staged reductions, 3 barriers ----------
__global__ __launch_bounds__(1024) void tape_kernel(const float* __restrict__ vals,
                                                    const float* __restrict__ keys,
                                                    const float* __restrict__ quer,
                                                    const float* __restrict__ acts,
                                                    float* __restrict__ Rout,
                                                    float* __restrict__ out_tape) {
  const int bid = blockIdx.x;          // 0..127
  const int b = bid >> 2, nt = bid & 3;
  const int tid = threadIdx.x;
  const int cid = tid & 63, lg = tid >> 6;   // lg 0..15
  __shared__ float tape[64][65], tkey[64][65];
  __shared__ float redA[16][64], redB[16][64], redC[16][64], redD[16][64];
  __shared__ float dv_s[64], dk_s[64];
  __shared__ float wpos_s[2][64], rpos_s[2][64], q_s[2][64];
  for (int i = tid; i < 64 * 65; i += 1024) { ((float*)tape)[i] = 0.f; ((float*)tkey)[i] = 0.f; }
  if (tid < 64) {
    wpos_s[0][tid] = (tid == 0) ? 1.f : 0.f;
    rpos_s[0][tid] = (tid == 0) ? 1.f : 0.f;
  }

  // prefetch t=0 inputs (v/k/q live in wave0 registers)
  float pv = 0.f, pk = 0.f, pq = 0.f;
  float2 pa0, pa1, pa2;
  {
    const size_t rc0 = ((size_t)b * 4 + nt) * 64;
    const float* a60 = acts + (size_t)b * 24 + nt * 6;
    if (tid < 64) { pv = vals[rc0 + tid]; pk = keys[rc0 + tid]; pq = quer[rc0 + tid]; }
    pa0 = *(const float2*)(a60); pa1 = *(const float2*)(a60 + 2); pa2 = *(const float2*)(a60 + 4);
  }
  if (tid < 64) q_s[0][tid] = pq;
  __syncthreads();

  for (int t = 0; t < 1024; ++t) {
    const int p = t & 1;
    const float v = pv, k = pk;
    const float rd0 = pa0.x, rd1 = pa0.y, wd0 = pa1.x, wd1 = pa1.y, rw0 = pa2.x, rw1 = pa2.y;
    const size_t rc = (((size_t)t * 32 + b) * 4 + nt) * 64;
    // prefetch t+1 (hidden behind the 3-barrier chain)
    {
      int tn = (t + 1 < 1024) ? t + 1 : 1023;
      const size_t rbn = (size_t)tn * 32 + b;
      const size_t rcn = (rbn * 4 + nt) * 64;
      const float* a6n = acts + rbn * 24 + nt * 6;
      if (tid < 64) { pv = vals[rcn + tid]; pk = keys[rcn + tid]; pq = quer[rcn + tid]; }
      pa0 = *(const float2*)(a6n); pa1 = *(const float2*)(a6n + 2); pa2 = *(const float2*)(a6n + 4);
    }
    // ---- phase 1: read-only partials, 4 rows per thread ----
    {
      float paA = 0.f, pbB = 0.f, prC = 0.f, pj = 0.f;
#pragma unroll
      for (int i = 0; i < 4; i++) {
        int l2 = lg * 4 + i;
        float tp = tape[l2][cid], tk = tkey[l2][cid];
        float wp = wpos_s[p][l2], rp = rpos_s[p][l2];
        paA = fmaf(tp, wp, paA); pbB = fmaf(tk, wp, pbB); prC = fmaf(tp, rp, prC);
        int c2 = lg * 4 + i;
        pj = fmaf(tkey[cid][c2], q_s[p][c2], pj);
      }
      redA[lg][cid] = paA; redB[lg][cid] = pbB; redC[lg][cid] = prC; redD[lg][cid] = pj;
    }
    __syncthreads();  // S_a
    // ---- phase 1b: wave0 computes dv/dk ----
    if (lg == 0) {
      float ov = 0.f, ok = 0.f;
#pragma unroll
      for (int j = 0; j < 16; j++) { ov += redA[j][cid]; ok += redB[j][cid]; }
      dv_s[cid] = (v - ov) * rw1;
      dk_s[cid] = (k - ok) * rw1;
    }
    __syncthreads();  // S_b
    // ---- phase 2: updates (all 16 waves) + distributed epilogues ----
    const float dvc = dv_s[cid], dkc = dk_s[cid];
#pragma unroll
    for (int i = 0; i < 4; i++) {
      int l2 = lg * 4 + i;
      float wp = wpos_s[p][l2];
      tape[l2][cid] = fmaf(wp, dvc, tape[l2][cid]);
      tkey[l2][cid] = fmaf(wp, dkc, tkey[l2][cid]);
    }
    if (lg == 0) {
      q_s[p ^ 1][cid] = pq;                        // publish q(t+1)
    } else if (lg == 1) {
      // read_out = (prC + (wpos.rpos)*dv) * rw0
      float prc = 0.f;
#pragma unroll
      for (int j = 0; j < 16; j++) prc += redC[j][cid];
      float sw = wpos_s[p][cid] * rpos_s[p][cid];
#pragma unroll
      for (int mm = 1; mm < 64; mm <<= 1) sw += __shfl_xor(sw, mm, 64);
      Rout[rc + cid] = fmaf(sw, dvc, prc) * rw0;
    } else if (lg == 2) {
      // jpos = jq + wpos*(dk.q); normalize (non-negative s = sum jp^2); advance pos
      float jq = 0.f;
#pragma unroll
      for (int j = 0; j < 16; j++) jq += redD[j][cid];
      float dq = dkc * q_s[p][cid];
#pragma unroll
      for (int mm = 1; mm < 64; mm <<= 1) dq += __shfl_xor(dq, mm, 64);
      float jp = fmaf(wpos_s[p][cid], dq, jq);
      float s = jp * jp;
#pragma unroll
      for (int mm = 1; mm < 64; mm <<= 1) s += __shfl_xor(s, mm, 64);
      jp /= fmaxf(sqrtf(s), 1e-12f);
      rpos_s[p ^ 1][cid] = rpos_s[p][cid] * rd0 + jp * rd1;
      wpos_s[p ^ 1][cid] = wpos_s[p][cid] * wd0 + jp * wd1;
    }
    __syncthreads();  // S_c
  }
  // final tape -> out_tape[(l*32+b)*256 + nt*64 + c]
  for (int i = tid; i < 4096; i += 1024) {
    int l2 = i >> 6, c2 = i & 63;
    out_tape[((size_t)l2 * 32 + b) * 256 + nt * 64 + c2] = tape[l2][c2];
  }
}

// ---------- launcher ----------
extern "C" void kernel_launch(void* const* d_in, const int* in_sizes, int n_in,
                              void* d_out, int out_size, void* d_ws, size_t ws_size,
                              hipStream_t stream) {
  const float* inputs = (const float*)d_in[0];
  const float* W_ih = (const float*)d_in[1];
  const float* W_hh = (const float*)d_in[2];
  const float* b_ih = (const float*)d_in[3];
  const float* b_hh = (const float*)d_in[4];
  const float* W_act = (const float*)d_in[5];
  const float* b_act = (const float*)d_in[6];
  const float* W_val = (const float*)d_in[7];
  const float* b_val = (const float*)d_in[8];
  const float* W_key = (const float*)d_in[9];
  const float* b_key = (const float*)d_in[10];
  const float* W_q = (const float*)d_in[11];
  const float* b_q = (const float*)d_in[12];
  const float* W_out = (const float*)d_in[13];
  const float* b_out = (const float*)d_in[14];

  if (ws_size < WS_NEED) {           // sentinel: absmax ~= 12345 tells us ws is too small
    sentinel_kernel<<<1, 1, 0, stream>>>((float*)d_out);
    return;
  }

  char* ws = (char*)d_ws;
  float* gxbuf = (float*)(ws + OFF_GX);
  float* Hc = (float*)(ws + OFF_HC);
  float* quer = (float*)(ws + OFF_QUER);
  float* acts = (float*)(ws + OFF_ACTS);
  float* R = (float*)(ws + OFF_R);
  unsigned short* hb16 = (unsigned short*)(ws + OFF_HB16);
  float* cbuf = (float*)(ws + OFF_CBUF);
  unsigned int* flags = (unsigned int*)(ws + OFF_FLAGS);

  float* keys = (float*)d_out;               // scratch in d_out (consumed by tape, then overwritten)
  float* vals = (float*)d_out + 8388608;
  float* out_tape = (float*)d_out + 16777216;

  dim3 blk(256);
  zero_flags_kernel<<<1, 64, 0, stream>>>(flags);

  gemm_f32bt_kernel<<<dim3(2, 256), blk, 0, stream>>>(inputs, W_val, vals, b_val, nullptr, 32768, 256, 512);
  gemm_f32bt_kernel<<<dim3(2, 256), blk, 0, stream>>>(inputs, W_key, keys, b_key, nullptr, 32768, 256, 512);
  norm64_kernel<<<32768, blk, 0, stream>>>(keys);

  for (int q = 0; q < 8; q++) {
    const float* Achunk = inputs + (size_t)q * 4096 * 512;
    gemm_f32bt_kernel<<<dim3(16, 32), blk, 0, stream>>>(Achunk, W_ih, gxbuf, b_ih, b_hh, 4096, 2048, 512);
    lstm_kernel<<<64, blk, 0, stream>>>(gxbuf, W_hh, hb16, cbuf, flags, Hc, q * 128);
    gemm_f32bt_kernel<<<dim3(2, 32), blk, 0, stream>>>(Hc, W_q, quer + (size_t)q * 4096 * 256, b_q, nullptr, 4096, 256, 512);
    actions_kernel<<<1024, blk, 0, stream>>>(Hc, W_act, b_act, acts + (size_t)q * 4096 * 24);
  }
  norm64_kernel<<<32768, blk, 0, stream>>>(quer);

  tape_kernel<<<128, 1024, 0, stream>>>(vals, keys, quer, acts, R, out_tape);

  gemm_f32bt_kernel<<<dim3(4, 256), blk, 0, stream>>>(R, W_out, (float*)d_out, b_out, nullptr, 32768, 512, 256);
}